// Round 3
// baseline (585.756 us; speedup 1.0000x reference)
//
#include <hip/hip_runtime.h>

#define N_NODES 100000
#define N_EDGES 1600000
#define IN_DIM 32
#define HID_DIM 64
#define OUT_DIM 8
#define BK 128                        // dst nodes per bucket
#define NBKT ((N_NODES + BK - 1) / BK)    // 782
#define QC 2560                       // per-bucket queue cap (mean 2048, ~11 sigma)
#define CHUNK 4096                    // edges per k_part2 block
#define NCHUNK ((N_EDGES + CHUNK - 1) / CHUNK)   // 391

typedef unsigned short u16;
typedef unsigned int u32;
typedef unsigned long long ull;

__device__ __forceinline__ float bf2f(u16 v) {
    return __uint_as_float(((u32)v) << 16);
}

__device__ __forceinline__ u16 f2bf(float f) {
    u32 u = __float_as_uint(f);
    u32 lsb = (u >> 16) & 1u;
    u += 0x7fffu + lsb;
    return (u16)(u >> 16);
}

__device__ __forceinline__ float ldf(const void* p, size_t i, int bf) {
    return bf ? bf2f(((const u16*)p)[i]) : ((const float*)p)[i];
}

// 8 bf16 dims (one uint4) -> LDS atomic accumulate
__device__ __forceinline__ void acc8(float* ar, int k0, uint4 r) {
    atomicAdd(&ar[k0 + 0], bf2f((u16)r.x)); atomicAdd(&ar[k0 + 1], bf2f((u16)(r.x >> 16)));
    atomicAdd(&ar[k0 + 2], bf2f((u16)r.y)); atomicAdd(&ar[k0 + 3], bf2f((u16)(r.y >> 16)));
    atomicAdd(&ar[k0 + 4], bf2f((u16)r.z)); atomicAdd(&ar[k0 + 5], bf2f((u16)(r.z >> 16)));
    atomicAdd(&ar[k0 + 6], bf2f((u16)r.w)); atomicAdd(&ar[k0 + 7], bf2f((u16)(r.w >> 16)));
}

__device__ __forceinline__ void acc4(float* ar, int k0, float4 v) {
    atomicAdd(&ar[k0 + 0], v.x); atomicAdd(&ar[k0 + 1], v.y);
    atomicAdd(&ar[k0 + 2], v.z); atomicAdd(&ar[k0 + 3], v.w);
}

// ---- Phase A: dtype probe + weight transpose + single-pass partition of
//      edges into 782 dst-buckets of 128 nodes (encode (src<<7)|d7).
//      R10-proven register-staged loop; LDS hist/lcur now full-width. ----
__global__ __launch_bounds__(256) void k_part2(
    const int* __restrict__ ei, const u32* __restrict__ xw,
    const void* __restrict__ W1l, const void* __restrict__ b1,
    const void* __restrict__ W1r,
    const void* __restrict__ W2l, const void* __restrict__ b2,
    const void* __restrict__ W2r,
    int* __restrict__ qcnt, u32* __restrict__ qbuf,
    float* __restrict__ tW1l, float* __restrict__ tW1r,
    float* __restrict__ tW2l, float* __restrict__ tW2r,
    float* __restrict__ tb1, float* __restrict__ tb2)
{
    __shared__ int shv, bfv;
    __shared__ int hist[NBKT], gbase[NBKT], lcur[NBKT];
    int t = threadIdx.x;
    if (t < 64) {   // proven dtype probe, executed per block (same data)
        int v = ei[2 * t + 1];
        ull m1 = __ballot(v == 0);
        u32 wd = xw[t];
        u32 b = (wd >> 8) & 0x7fu;
        ull m2 = __ballot(b >= 0x38u && b <= 0x41u);
        if (t == 0) {
            shv = (m1 == ~0ULL) ? 1 : 0;
            bfv = (__popcll(m2) >= 56) ? 1 : 0;
        }
    }
    for (int i = t; i < NBKT; i += 256) { hist[i] = 0; lcur[i] = 0; }
    __syncthreads();
    int sh = shv, bf = bfv;

    if (blockIdx.x < 16) {        // weight transpose duty (R11-proven indexing)
        for (int i = blockIdx.x * 256 + t; i < HID_DIM * IN_DIM; i += 16 * 256) {
            int o = i / IN_DIM, k = i % IN_DIM;
            tW1l[k * HID_DIM + o] = ldf(W1l, i, bf);
            tW1r[k * HID_DIM + o] = ldf(W1r, i, bf);
        }
        for (int i = blockIdx.x * 256 + t; i < OUT_DIM * HID_DIM; i += 16 * 256) {
            int o = i / HID_DIM, k = i % HID_DIM;
            tW2l[k * OUT_DIM + o] = ldf(W2l, i, bf);
            tW2r[k * OUT_DIM + o] = ldf(W2r, i, bf);
        }
        if (blockIdx.x == 0) {
            if (t < HID_DIM) tb1[t] = ldf(b1, t, bf);
            if (t < OUT_DIM) tb2[t] = ldf(b2, t, bf);
        }
    }

    // edge partition (register-staged, R10-proven shape)
    int e0 = blockIdx.x * CHUNK;
    int myd[16], mys[16];
    #pragma unroll
    for (int i = 0; i < 16; i++) {
        int e = e0 + i * 256 + t;
        if (e < N_EDGES) {
            size_t off = (size_t)e << sh;
            mys[i] = ei[off];
            int d = ei[((size_t)N_EDGES << sh) + off];
            myd[i] = d;
            atomicAdd(&hist[d >> 7], 1);
        } else myd[i] = -1;
    }
    __syncthreads();
    for (int i = t; i < NBKT; i += 256) {
        int h = hist[i];
        gbase[i] = h ? atomicAdd(&qcnt[i], h) : 0;
    }
    __syncthreads();
    #pragma unroll
    for (int i = 0; i < 16; i++) {
        int d = myd[i];
        if (d >= 0) {
            int bk = d >> 7;
            int p = gbase[bk] + atomicAdd(&lcur[bk], 1);
            if (p < QC)
                qbuf[(size_t)bk * QC + p] = ((u32)mys[i] << 7) | (u32)(d & 127);
        }
    }
}

// ---- Layer 1: one bucket (128 dst nodes) per block. Gather x[src] rows,
//      LDS-atomic accumulate into agg[128][33] f32 (pad 33 -> bank =
//      (33*d7+k)%32 spreads via random d7), deg in LDS; then the proven
//      dense1+relu+proj2 code over the bucket's contiguous nodes. ----
__global__ __launch_bounds__(256, 4) void k_l1(
    const void* __restrict__ x,
    const int* __restrict__ qcnt, const u32* __restrict__ qbuf,
    const float* __restrict__ tW1l, const float* __restrict__ tW1r,
    const float* __restrict__ tW2l, const float* __restrict__ tW2r,
    const float* __restrict__ tb1, const float* __restrict__ tb2,
    u16* __restrict__ gbuf, float* __restrict__ rbuf,
    const u32* __restrict__ xw)
{
    __shared__ float agg[BK][IN_DIM + 1];   // 16.9 KB
    __shared__ float xs[BK][IN_DIM];        // 16 KB
    __shared__ float hb[8][HID_DIM + 1];    // 2 KB, wave-private rows
    __shared__ int degi[BK];
    __shared__ int bfv;

    int t = threadIdx.x;
    if (t < 64) {   // dtype probe (proven)
        u32 wd = xw[t];
        u32 b = (wd >> 8) & 0x7fu;
        ull m2 = __ballot(b >= 0x38u && b <= 0x41u);
        if (t == 0) bfv = (__popcll(m2) >= 56) ? 1 : 0;
    }
    for (int i = t; i < BK * (IN_DIM + 1); i += 256) ((float*)agg)[i] = 0.0f;
    for (int i = t; i < BK; i += 256) degi[i] = 0;
    __syncthreads();
    int bf = bfv;
    int b = blockIdx.x, nb = b * BK;

    // stage self rows -> xs (f32), guarded for the partial last bucket
    if (bf) {
        const u32* xr = (const u32*)x + (size_t)nb * (IN_DIM / 2);
        for (int i = t; i < BK * (IN_DIM / 2); i += 256) {
            int r = i >> 4, c = i & 15;
            u32 w = (nb + r < N_NODES) ? xr[i] : 0u;
            xs[r][2 * c]     = bf2f((u16)w);
            xs[r][2 * c + 1] = bf2f((u16)(w >> 16));
        }
    } else {
        const float* xr = (const float*)x + (size_t)nb * IN_DIM;
        for (int i = t; i < BK * IN_DIM; i += 256) {
            xs[i >> 5][i & 31] = (nb + (i >> 5) < N_NODES) ? xr[i] : 0.0f;
        }
    }
    // no barrier needed yet: xs consumed only after the gather barrier

    // gather + LDS accumulate
    int m = qcnt[b]; if (m > QC) m = QC;
    const u32* q = qbuf + (size_t)b * QC;
    if (bf) {
        int i = t;
        for (; i + 256 < m; i += 512) {   // 2 edges in flight: 8 loads of 16B
            u32 uA = __builtin_nontemporal_load(&q[i]);
            u32 uB = __builtin_nontemporal_load(&q[i + 256]);
            int dA = uA & 127, sA = (int)(uA >> 7);
            int dB = uB & 127, sB = (int)(uB >> 7);
            const uint4* rA = (const uint4*)((const u16*)x + (size_t)sA * IN_DIM);
            const uint4* rB = (const uint4*)((const u16*)x + (size_t)sB * IN_DIM);
            uint4 a0 = rA[0], a1 = rA[1], a2 = rA[2], a3 = rA[3];
            uint4 b0 = rB[0], b1_ = rB[1], b2_ = rB[2], b3 = rB[3];
            atomicAdd(&degi[dA], 1); atomicAdd(&degi[dB], 1);
            float* arA = agg[dA];
            acc8(arA, 0, a0); acc8(arA, 8, a1); acc8(arA, 16, a2); acc8(arA, 24, a3);
            float* arB = agg[dB];
            acc8(arB, 0, b0); acc8(arB, 8, b1_); acc8(arB, 16, b2_); acc8(arB, 24, b3);
        }
        if (i < m) {
            u32 u = __builtin_nontemporal_load(&q[i]);
            int d7 = u & 127, s = (int)(u >> 7);
            const uint4* r = (const uint4*)((const u16*)x + (size_t)s * IN_DIM);
            uint4 a0 = r[0], a1 = r[1], a2 = r[2], a3 = r[3];
            atomicAdd(&degi[d7], 1);
            float* ar = agg[d7];
            acc8(ar, 0, a0); acc8(ar, 8, a1); acc8(ar, 16, a2); acc8(ar, 24, a3);
        }
    } else {
        for (int i = t; i < m; i += 256) {
            u32 u = __builtin_nontemporal_load(&q[i]);
            int d7 = u & 127, s = (int)(u >> 7);
            const float4* r = (const float4*)((const float*)x + (size_t)s * IN_DIM);
            float4 v0 = r[0], v1 = r[1], v2 = r[2], v3 = r[3];
            float4 v4 = r[4], v5 = r[5], v6 = r[6], v7 = r[7];
            atomicAdd(&degi[d7], 1);
            float* ar = agg[d7];
            acc4(ar, 0, v0);  acc4(ar, 4, v1);  acc4(ar, 8, v2);  acc4(ar, 12, v3);
            acc4(ar, 16, v4); acc4(ar, 20, v5); acc4(ar, 24, v6); acc4(ar, 28, v7);
        }
    }
    __syncthreads();

    // dense layer 1 + proj (proven code), 16 node-pair iterations per wave
    int wid = t >> 6, lane = t & 63;
    int o = lane;
    float bb = tb1[o];
    int half = lane >> 5, g2 = (lane >> 3) & 3, l = lane & 7;
    for (int pr = 0; pr < 16; pr++) {
        int s0 = pr * 8 + wid * 2, s1 = s0 + 1;
        float rd0 = 1.0f / fmaxf((float)degi[s0], 1.0f);
        float rd1 = 1.0f / fmaxf((float)degi[s1], 1.0f);
        float acc0 = bb, acc1 = bb;
        #pragma unroll 8
        for (int k = 0; k < IN_DIM; k++) {
            float wl = tW1l[k * HID_DIM + o];
            float wr = tW1r[k * HID_DIM + o];
            acc0 += (agg[s0][k] * rd0) * wl + xs[s0][k] * wr;
            acc1 += (agg[s1][k] * rd1) * wl + xs[s1][k] * wr;
        }
        hb[wid * 2][o]     = fmaxf(acc0, 0.0f);   // wave-private rows: no barrier
        hb[wid * 2 + 1][o] = fmaxf(acc1, 0.0f);
        int hs = wid * 2 + half;
        float ga = 0.0f, ra = 0.0f;
        #pragma unroll 4
        for (int mm = 0; mm < 16; mm++) {
            int k = g2 * 16 + mm;
            float hv = hb[hs][k];
            ga += hv * tW2l[k * OUT_DIM + l];
            ra += hv * tW2r[k * OUT_DIM + l];
        }
        ga += __shfl_xor(ga, 8, 64);  ga += __shfl_xor(ga, 16, 64);
        ra += __shfl_xor(ra, 8, 64);  ra += __shfl_xor(ra, 16, 64);
        int n = nb + s0 + half;
        if (g2 == 0 && n < N_NODES) {
            __builtin_nontemporal_store(f2bf(ga), &gbuf[(size_t)n * OUT_DIM + l]);
            __builtin_nontemporal_store(ra + tb2[l], &rbuf[(size_t)n * OUT_DIM + l]);
        }
    }
}

// ---- Layer 2: one bucket per block. Gather g[src] (16B rows, 1.6MB table),
//      LDS-atomic accumulate agg8[128][9], recount deg, write out. ----
__global__ __launch_bounds__(256) void k_l2(
    const u16* __restrict__ gbuf, const float* __restrict__ rbuf,
    const int* __restrict__ qcnt, const u32* __restrict__ qbuf,
    const u32* __restrict__ xw, void* __restrict__ out)
{
    __shared__ float ag[BK][OUT_DIM + 1];   // 4.5 KB, pad 9 spreads banks
    __shared__ int degi[BK];
    __shared__ int bfv;
    int t = threadIdx.x;
    if (t < 64) {   // output-dtype probe (proven)
        u32 w = xw[t];
        u32 b = (w >> 8) & 0x7fu;
        ull m2 = __ballot(b >= 0x38u && b <= 0x41u);
        if (t == 0) bfv = (__popcll(m2) >= 56) ? 1 : 0;
    }
    for (int i = t; i < BK * (OUT_DIM + 1); i += 256) ((float*)ag)[i] = 0.0f;
    for (int i = t; i < BK; i += 256) degi[i] = 0;
    __syncthreads();
    int b = blockIdx.x, nb = b * BK;
    int m = qcnt[b]; if (m > QC) m = QC;
    const u32* q = qbuf + (size_t)b * QC;
    int i = t;
    for (; i + 256 < m; i += 512) {          // 2 edges in flight
        u32 uA = __builtin_nontemporal_load(&q[i]);
        u32 uB = __builtin_nontemporal_load(&q[i + 256]);
        int dA = uA & 127, sA = (int)(uA >> 7);
        int dB = uB & 127, sB = (int)(uB >> 7);
        uint4 rA = *(const uint4*)(gbuf + (size_t)sA * OUT_DIM);
        uint4 rB = *(const uint4*)(gbuf + (size_t)sB * OUT_DIM);
        atomicAdd(&degi[dA], 1); atomicAdd(&degi[dB], 1);
        acc8(ag[dA], 0, rA);
        acc8(ag[dB], 0, rB);
    }
    if (i < m) {
        u32 u = __builtin_nontemporal_load(&q[i]);
        int d7 = u & 127, s = (int)(u >> 7);
        uint4 r = *(const uint4*)(gbuf + (size_t)s * OUT_DIM);
        atomicAdd(&degi[d7], 1);
        acc8(ag[d7], 0, r);
    }
    __syncthreads();
    for (int idx = t; idx < BK * OUT_DIM; idx += 256) {
        int r = idx >> 3, l = idx & 7;
        int n = nb + r;
        if (n < N_NODES) {
            float res = ag[r][l] / fmaxf((float)degi[r], 1.0f)
                      + rbuf[(size_t)n * OUT_DIM + l];
            size_t oi = (size_t)n * OUT_DIM + l;
            if (bfv) ((u16*)out)[oi] = f2bf(res);
            else     ((float*)out)[oi] = res;
        }
    }
}

extern "C" void kernel_launch(void* const* d_in, const int* in_sizes, int n_in,
                              void* d_out, int out_size, void* d_ws, size_t ws_size,
                              hipStream_t stream) {
    const void* x   = d_in[0];
    const int*  ei  = (const int*)d_in[1];
    const void* W1l = d_in[2];
    const void* b1  = d_in[3];
    const void* W1r = d_in[4];
    const void* W2l = d_in[5];
    const void* b2  = d_in[6];
    const void* W2r = d_in[7];

    // ws layout (4B units); total ~13 MB (ws >= 64.4 MB proven earlier)
    int* qcnt    = (int*)d_ws;                       // 1024 (memset, 782 used)
    float* tW1l  = (float*)(qcnt + 1024);            // 2048
    float* tW1r  = tW1l + IN_DIM * HID_DIM;          // 2048
    float* tW2l  = tW1r + IN_DIM * HID_DIM;          // 512
    float* tW2r  = tW2l + HID_DIM * OUT_DIM;         // 512
    float* tb1   = tW2r + HID_DIM * OUT_DIM;         // 64
    float* tb2   = tb1 + HID_DIM;                    // 8
    u32* qbuf    = (u32*)(tb2 + OUT_DIM);            // NBKT*QC (8.0 MB, 16B-aligned)
    u16* gbuf    = (u16*)(qbuf + (size_t)NBKT * QC);           // N*8 u16 (1.6 MB)
    float* rbuf  = (float*)(gbuf + (size_t)N_NODES * OUT_DIM); // N*8 f32 (3.2 MB)

    // zero qcnt only (4 KB)
    hipMemsetAsync(d_ws, 0, 1024 * sizeof(int), stream);

    k_part2<<<NCHUNK, 256, 0, stream>>>(ei, (const u32*)x,
                                        W1l, b1, W1r, W2l, b2, W2r,
                                        qcnt, qbuf,
                                        tW1l, tW1r, tW2l, tW2r, tb1, tb2);
    k_l1<<<NBKT, 256, 0, stream>>>(x, qcnt, qbuf,
                                   tW1l, tW1r, tW2l, tW2r, tb1, tb2,
                                   gbuf, rbuf, (const u32*)x);
    k_l2<<<NBKT, 256, 0, stream>>>(gbuf, rbuf, qcnt, qbuf,
                                   (const u32*)x, d_out);
}

// Round 5
// 218.030 us; speedup vs baseline: 2.6866x; 2.6866x over previous
//
#include <hip/hip_runtime.h>

#define N_NODES 100000
#define N_EDGES 1600000
#define IN_DIM 32
#define HID_DIM 64
#define OUT_DIM 8
#define BK 128                        // dst nodes per bucket
#define NBKT ((N_NODES + BK - 1) / BK)    // 782
#define QC 2560                       // per-bucket queue cap (mean 2048, ~11 sigma)
#define CHUNK 4096                    // edges per k_part2 block
#define NCHUNK ((N_EDGES + CHUNK - 1) / CHUNK)   // 391

typedef unsigned short u16;
typedef unsigned int u32;
typedef unsigned long long ull;

__device__ __forceinline__ float bf2f(u16 v) {
    return __uint_as_float(((u32)v) << 16);
}

__device__ __forceinline__ u16 f2bf(float f) {
    u32 u = __float_as_uint(f);
    u32 lsb = (u >> 16) & 1u;
    u += 0x7fffu + lsb;
    return (u16)(u >> 16);
}

__device__ __forceinline__ float ldf(const void* p, size_t i, int bf) {
    return bf ? bf2f(((const u16*)p)[i]) : ((const float*)p)[i];
}

// ---- Phase A (R3-proven): dtype probe + weight transpose + single-pass
//      partition of edges into 782 dst-buckets of 128 nodes ((src<<7)|d7). ----
__global__ __launch_bounds__(256) void k_part2(
    const int* __restrict__ ei, const u32* __restrict__ xw,
    const void* __restrict__ W1l, const void* __restrict__ b1,
    const void* __restrict__ W1r,
    const void* __restrict__ W2l, const void* __restrict__ b2,
    const void* __restrict__ W2r,
    int* __restrict__ qcnt, u32* __restrict__ qbuf,
    float* __restrict__ tW1l, float* __restrict__ tW1r,
    float* __restrict__ tW2l, float* __restrict__ tW2r,
    float* __restrict__ tb1, float* __restrict__ tb2)
{
    __shared__ int shv, bfv;
    __shared__ int hist[NBKT], gbase[NBKT], lcur[NBKT];
    int t = threadIdx.x;
    if (t < 64) {   // proven dtype probe, executed per block (same data)
        int v = ei[2 * t + 1];
        ull m1 = __ballot(v == 0);
        u32 wd = xw[t];
        u32 b = (wd >> 8) & 0x7fu;
        ull m2 = __ballot(b >= 0x38u && b <= 0x41u);
        if (t == 0) {
            shv = (m1 == ~0ULL) ? 1 : 0;
            bfv = (__popcll(m2) >= 56) ? 1 : 0;
        }
    }
    for (int i = t; i < NBKT; i += 256) { hist[i] = 0; lcur[i] = 0; }
    __syncthreads();
    int sh = shv, bf = bfv;

    if (blockIdx.x < 16) {        // weight transpose duty (R11-proven indexing)
        for (int i = blockIdx.x * 256 + t; i < HID_DIM * IN_DIM; i += 16 * 256) {
            int o = i / IN_DIM, k = i % IN_DIM;
            tW1l[k * HID_DIM + o] = ldf(W1l, i, bf);
            tW1r[k * HID_DIM + o] = ldf(W1r, i, bf);
        }
        for (int i = blockIdx.x * 256 + t; i < OUT_DIM * HID_DIM; i += 16 * 256) {
            int o = i / HID_DIM, k = i % HID_DIM;
            tW2l[k * OUT_DIM + o] = ldf(W2l, i, bf);
            tW2r[k * OUT_DIM + o] = ldf(W2r, i, bf);
        }
        if (blockIdx.x == 0) {
            if (t < HID_DIM) tb1[t] = ldf(b1, t, bf);
            if (t < OUT_DIM) tb2[t] = ldf(b2, t, bf);
        }
    }

    // edge partition (register-staged, R10-proven shape)
    int e0 = blockIdx.x * CHUNK;
    int myd[16], mys[16];
    #pragma unroll
    for (int i = 0; i < 16; i++) {
        int e = e0 + i * 256 + t;
        if (e < N_EDGES) {
            size_t off = (size_t)e << sh;
            mys[i] = ei[off];
            int d = ei[((size_t)N_EDGES << sh) + off];
            myd[i] = d;
            atomicAdd(&hist[d >> 7], 1);
        } else myd[i] = -1;
    }
    __syncthreads();
    for (int i = t; i < NBKT; i += 256) {
        int h = hist[i];
        gbase[i] = h ? atomicAdd(&qcnt[i], h) : 0;
    }
    __syncthreads();
    #pragma unroll
    for (int i = 0; i < 16; i++) {
        int d = myd[i];
        if (d >= 0) {
            int bk = d >> 7;
            int p = gbase[bk] + atomicAdd(&lcur[bk], 1);
            if (p < QC)
                qbuf[(size_t)bk * QC + p] = ((u32)mys[i] << 7) | (u32)(d & 127);
        }
    }
}

// ---- Layer 1: one bucket (128 dst nodes) per block.
//      (1) LDS counting sort of the bucket's edges by dst (NO per-element
//          atomics on the accumulate path — R3's 408us lesson).
//      (2) R0-proven register-accumulate gather (4-way ILP), slot indices
//          now read from sorted LDS lists.
//      (3) R3-proven dense1+relu+proj2 per node pair, wave-private bufs. ----
__global__ __launch_bounds__(256, 4) void k_l1(
    const void* __restrict__ x,
    const int* __restrict__ qcnt, const u32* __restrict__ qbuf,
    const float* __restrict__ tW1l, const float* __restrict__ tW1r,
    const float* __restrict__ tW2l, const float* __restrict__ tW2r,
    const float* __restrict__ tb1, const float* __restrict__ tb2,
    u16* __restrict__ gbuf, float* __restrict__ rbuf,
    const u32* __restrict__ xw)
{
    __shared__ int hist[BK], pos[BK], pcur[BK];
    __shared__ u32 srt[QC];                 // 10.2 KB sorted src lists
    __shared__ float xs[BK][IN_DIM];        // 16 KB self rows (f32)
    __shared__ float aggw[8][2][IN_DIM];    // 2 KB wave-private agg pair
    __shared__ float hb[8][HID_DIM + 1];    // 2 KB wave-private h rows
    __shared__ int wtot, bfv;

    int t = threadIdx.x;
    if (t < 64) {   // dtype probe (proven)
        u32 wd = xw[t];
        u32 b = (wd >> 8) & 0x7fu;
        ull m2 = __ballot(b >= 0x38u && b <= 0x41u);
        if (t == 0) bfv = (__popcll(m2) >= 56) ? 1 : 0;
    }
    if (t < BK) hist[t] = 0;
    __syncthreads();
    int bf = bfv;
    int b = blockIdx.x, nb = b * BK;
    int m = qcnt[b]; if (m > QC) m = QC; if (m < 0) m = 0;
    const u32* q = qbuf + (size_t)b * QC;

    // stage self rows -> xs (f32), guarded for the partial last bucket
    if (bf) {
        const u32* xr = (const u32*)x + (size_t)nb * (IN_DIM / 2);
        int lim = ((N_NODES - nb < BK) ? (N_NODES - nb) : BK) * (IN_DIM / 2);
        for (int i = t; i < BK * (IN_DIM / 2); i += 256) {
            u32 w = (i < lim) ? xr[i] : 0u;
            int r = i >> 4, c = i & 15;
            xs[r][2 * c]     = bf2f((u16)w);
            xs[r][2 * c + 1] = bf2f((u16)(w >> 16));
        }
    } else {
        const float* xr = (const float*)x + (size_t)nb * IN_DIM;
        int lim = ((N_NODES - nb < BK) ? (N_NODES - nb) : BK) * IN_DIM;
        for (int i = t; i < BK * IN_DIM; i += 256)
            xs[i >> 5][i & 31] = (i < lim) ? xr[i] : 0.0f;
    }

    // ---- counting sort: histogram -> scan -> scatter ----
    for (int i = t; i < m; i += 256)
        atomicAdd(&hist[q[i] & 127], 1);          // ~2K atomics total, cheap
    __syncthreads();
    int inc = 0, v = 0;
    if (t < 128) {                                 // 2-wave scan of 128 bins
        v = hist[t]; inc = v;
        #pragma unroll
        for (int o = 1; o < 64; o <<= 1) {
            int y = __shfl_up(inc, o, 64);
            if ((t & 63) >= o) inc += y;
        }
        if (t == 63) wtot = inc;
    }
    __syncthreads();
    if (t < 128) {
        int ex = ((t >= 64) ? wtot : 0) + inc - v;
        pos[t] = ex; pcur[t] = ex;
    }
    __syncthreads();
    for (int i = t; i < m; i += 256) {            // scatter src into sorted lists
        u32 u = q[i];                             // L2-hot second pass
        int p = atomicAdd(&pcur[u & 127], 1);
        srt[p] = u >> 7;
    }
    __syncthreads();

    // ---- per-pair gather (R0-proven loop, LDS slot lists) + dense + proj ----
    int wid = t >> 6, lane = t & 63;
    int half = lane >> 5, g2 = (lane >> 3) & 3, l = lane & 7;
    int o = lane;
    float bb = tb1[o];
    for (int pr = 0; pr < 16; pr++) {
        int s0 = pr * 8 + wid * 2;
        int ns = s0 + half;
        int st = pos[ns], deg = hist[ns];
        float a0 = 0, a1 = 0, a2 = 0, a3 = 0;
        float c0 = 0, c1 = 0, c2 = 0, c3 = 0;
        float d0 = 0, d1 = 0, d2 = 0, d3 = 0;
        float e0 = 0, e1 = 0, e2 = 0, e3 = 0;
        int j = g2;
        for (; j + 12 < deg; j += 16) {   // 4 independent neighbor loads in flight
            int sA = (int)srt[st + j];
            int sB = (int)srt[st + j + 4];
            int sC = (int)srt[st + j + 8];
            int sD = (int)srt[st + j + 12];
            if (bf) {
                ushort4 vA = reinterpret_cast<const ushort4*>((const u16*)x + (size_t)sA * IN_DIM)[l];
                ushort4 vB = reinterpret_cast<const ushort4*>((const u16*)x + (size_t)sB * IN_DIM)[l];
                ushort4 vC = reinterpret_cast<const ushort4*>((const u16*)x + (size_t)sC * IN_DIM)[l];
                ushort4 vD = reinterpret_cast<const ushort4*>((const u16*)x + (size_t)sD * IN_DIM)[l];
                a0 += bf2f(vA.x); a1 += bf2f(vA.y); a2 += bf2f(vA.z); a3 += bf2f(vA.w);
                c0 += bf2f(vB.x); c1 += bf2f(vB.y); c2 += bf2f(vB.z); c3 += bf2f(vB.w);
                d0 += bf2f(vC.x); d1 += bf2f(vC.y); d2 += bf2f(vC.z); d3 += bf2f(vC.w);
                e0 += bf2f(vD.x); e1 += bf2f(vD.y); e2 += bf2f(vD.z); e3 += bf2f(vD.w);
            } else {
                float4 vA = reinterpret_cast<const float4*>((const float*)x + (size_t)sA * IN_DIM)[l];
                float4 vB = reinterpret_cast<const float4*>((const float*)x + (size_t)sB * IN_DIM)[l];
                float4 vC = reinterpret_cast<const float4*>((const float*)x + (size_t)sC * IN_DIM)[l];
                float4 vD = reinterpret_cast<const float4*>((const float*)x + (size_t)sD * IN_DIM)[l];
                a0 += vA.x; a1 += vA.y; a2 += vA.z; a3 += vA.w;
                c0 += vB.x; c1 += vB.y; c2 += vB.z; c3 += vB.w;
                d0 += vC.x; d1 += vC.y; d2 += vC.z; d3 += vC.w;
                e0 += vD.x; e1 += vD.y; e2 += vD.z; e3 += vD.w;
            }
        }
        for (; j + 4 < deg; j += 8) {     // 2-way remainder
            int sA = (int)srt[st + j];
            int sB = (int)srt[st + j + 4];
            if (bf) {
                ushort4 vA = reinterpret_cast<const ushort4*>((const u16*)x + (size_t)sA * IN_DIM)[l];
                ushort4 vB = reinterpret_cast<const ushort4*>((const u16*)x + (size_t)sB * IN_DIM)[l];
                a0 += bf2f(vA.x); a1 += bf2f(vA.y); a2 += bf2f(vA.z); a3 += bf2f(vA.w);
                c0 += bf2f(vB.x); c1 += bf2f(vB.y); c2 += bf2f(vB.z); c3 += bf2f(vB.w);
            } else {
                float4 vA = reinterpret_cast<const float4*>((const float*)x + (size_t)sA * IN_DIM)[l];
                float4 vB = reinterpret_cast<const float4*>((const float*)x + (size_t)sB * IN_DIM)[l];
                a0 += vA.x; a1 += vA.y; a2 += vA.z; a3 += vA.w;
                c0 += vB.x; c1 += vB.y; c2 += vB.z; c3 += vB.w;
            }
        }
        if (j < deg) {                    // tail (at most one per group)
            int s = (int)srt[st + j];
            if (bf) {
                ushort4 vv = reinterpret_cast<const ushort4*>((const u16*)x + (size_t)s * IN_DIM)[l];
                a0 += bf2f(vv.x); a1 += bf2f(vv.y); a2 += bf2f(vv.z); a3 += bf2f(vv.w);
            } else {
                float4 vv = reinterpret_cast<const float4*>((const float*)x + (size_t)s * IN_DIM)[l];
                a0 += vv.x; a1 += vv.y; a2 += vv.z; a3 += vv.w;
            }
        }
        a0 += c0 + d0 + e0;
        a1 += c1 + d1 + e1;
        a2 += c2 + d2 + e2;
        a3 += c3 + d3 + e3;
        a0 += __shfl_xor(a0, 8, 64);  a0 += __shfl_xor(a0, 16, 64);
        a1 += __shfl_xor(a1, 8, 64);  a1 += __shfl_xor(a1, 16, 64);
        a2 += __shfl_xor(a2, 8, 64);  a2 += __shfl_xor(a2, 16, 64);
        a3 += __shfl_xor(a3, 8, 64);  a3 += __shfl_xor(a3, 16, 64);
        if (g2 == 0) {                    // wave-private: no barrier needed
            aggw[wid][half][4 * l + 0] = a0; aggw[wid][half][4 * l + 1] = a1;
            aggw[wid][half][4 * l + 2] = a2; aggw[wid][half][4 * l + 3] = a3;
        }
        // dense layer 1 (each lane = output o, both nodes of the pair)
        float rd0 = 1.0f / fmaxf((float)hist[s0], 1.0f);
        float rd1 = 1.0f / fmaxf((float)hist[s0 + 1], 1.0f);
        float acc0 = bb, acc1 = bb;
        #pragma unroll 8
        for (int k = 0; k < IN_DIM; k++) {
            float wl = tW1l[k * HID_DIM + o];
            float wr = tW1r[k * HID_DIM + o];
            acc0 += (aggw[wid][0][k] * rd0) * wl + xs[s0][k] * wr;
            acc1 += (aggw[wid][1][k] * rd1) * wl + xs[s0 + 1][k] * wr;
        }
        hb[wid * 2][o]     = fmaxf(acc0, 0.0f);   // wave-private rows
        hb[wid * 2 + 1][o] = fmaxf(acc1, 0.0f);
        // layer-2 projections: g = h@W2l^T (bf16-packed), r = h@W2r^T + b2
        int hs = wid * 2 + half;
        float ga = 0.0f, ra = 0.0f;
        #pragma unroll 4
        for (int mm = 0; mm < 16; mm++) {
            int k = g2 * 16 + mm;
            float hv = hb[hs][k];
            ga += hv * tW2l[k * OUT_DIM + l];
            ra += hv * tW2r[k * OUT_DIM + l];
        }
        ga += __shfl_xor(ga, 8, 64);  ga += __shfl_xor(ga, 16, 64);
        ra += __shfl_xor(ra, 8, 64);  ra += __shfl_xor(ra, 16, 64);
        int n = nb + ns;
        if (g2 == 0 && n < N_NODES) {
            __builtin_nontemporal_store(f2bf(ga), &gbuf[(size_t)n * OUT_DIM + l]);
            __builtin_nontemporal_store(ra + tb2[l], &rbuf[(size_t)n * OUT_DIM + l]);
        }
    }
}

// ---- Layer 2: one bucket per block. Same counting sort, then gather
//      g[src] rows (L2-resident 1.6MB) with the R0-proven 8-lane/node
//      4-way-ILP loop; out = mean + r. ----
__global__ __launch_bounds__(256) void k_l2(
    const u16* __restrict__ gbuf, const float* __restrict__ rbuf,
    const int* __restrict__ qcnt, const u32* __restrict__ qbuf,
    const u32* __restrict__ xw, void* __restrict__ out)
{
    __shared__ int hist[BK], pos[BK], pcur[BK];
    __shared__ u32 srt[QC];
    __shared__ int wtot, bfv;
    int t = threadIdx.x;
    if (t < 64) {   // output-dtype probe (proven)
        u32 w = xw[t];
        u32 b = (w >> 8) & 0x7fu;
        ull m2 = __ballot(b >= 0x38u && b <= 0x41u);
        if (t == 0) bfv = (__popcll(m2) >= 56) ? 1 : 0;
    }
    if (t < BK) hist[t] = 0;
    __syncthreads();
    int b = blockIdx.x, nb = b * BK;
    int m = qcnt[b]; if (m > QC) m = QC; if (m < 0) m = 0;
    const u32* q = qbuf + (size_t)b * QC;

    for (int i = t; i < m; i += 256)
        atomicAdd(&hist[q[i] & 127], 1);
    __syncthreads();
    int inc = 0, v = 0;
    if (t < 128) {
        v = hist[t]; inc = v;
        #pragma unroll
        for (int o = 1; o < 64; o <<= 1) {
            int y = __shfl_up(inc, o, 64);
            if ((t & 63) >= o) inc += y;
        }
        if (t == 63) wtot = inc;
    }
    __syncthreads();
    if (t < 128) {
        int ex = ((t >= 64) ? wtot : 0) + inc - v;
        pos[t] = ex; pcur[t] = ex;
    }
    __syncthreads();
    for (int i = t; i < m; i += 256) {
        u32 u = q[i];
        int p = atomicAdd(&pcur[u & 127], 1);
        srt[p] = u >> 7;
    }
    __syncthreads();

    int grp = t >> 3, l = t & 7;          // 32 groups x 8 lanes
    for (int r = 0; r < 4; r++) {
        int ns = grp * 4 + r;             // node slot 0..127
        int st = pos[ns], deg = hist[ns];
        float a0 = 0.0f, a1 = 0.0f, a2 = 0.0f, a3 = 0.0f;
        int j = 0;
        for (; j + 3 < deg; j += 4) {
            int v0 = (int)srt[st + j];
            int v1 = (int)srt[st + j + 1];
            int v2 = (int)srt[st + j + 2];
            int v3 = (int)srt[st + j + 3];
            a0 += bf2f(gbuf[(size_t)v0 * OUT_DIM + l]);
            a1 += bf2f(gbuf[(size_t)v1 * OUT_DIM + l]);
            a2 += bf2f(gbuf[(size_t)v2 * OUT_DIM + l]);
            a3 += bf2f(gbuf[(size_t)v3 * OUT_DIM + l]);
        }
        for (; j < deg; j++) a0 += bf2f(gbuf[(size_t)srt[st + j] * OUT_DIM + l]);
        int n = nb + ns;
        if (n < N_NODES) {
            float res = (a0 + a1 + a2 + a3) / fmaxf((float)deg, 1.0f)
                      + rbuf[(size_t)n * OUT_DIM + l];
            size_t oi = (size_t)n * OUT_DIM + l;
            if (bfv) ((u16*)out)[oi] = f2bf(res);
            else     ((float*)out)[oi] = res;
        }
    }
}

extern "C" void kernel_launch(void* const* d_in, const int* in_sizes, int n_in,
                              void* d_out, int out_size, void* d_ws, size_t ws_size,
                              hipStream_t stream) {
    const void* x   = d_in[0];
    const int*  ei  = (const int*)d_in[1];
    const void* W1l = d_in[2];
    const void* b1  = d_in[3];
    const void* W1r = d_in[4];
    const void* W2l = d_in[5];
    const void* b2  = d_in[6];
    const void* W2r = d_in[7];

    // ws layout (4B units); total ~13 MB (ws >= 64.4 MB proven earlier)
    int* qcnt    = (int*)d_ws;                       // 1024 (memset, 782 used)
    float* tW1l  = (float*)(qcnt + 1024);            // 2048
    float* tW1r  = tW1l + IN_DIM * HID_DIM;          // 2048
    float* tW2l  = tW1r + IN_DIM * HID_DIM;          // 512
    float* tW2r  = tW2l + HID_DIM * OUT_DIM;         // 512
    float* tb1   = tW2r + HID_DIM * OUT_DIM;         // 64
    float* tb2   = tb1 + HID_DIM;                    // 8
    u32* qbuf    = (u32*)(tb2 + OUT_DIM);            // NBKT*QC (8.0 MB, 16B-aligned)
    u16* gbuf    = (u16*)(qbuf + (size_t)NBKT * QC);           // N*8 u16 (1.6 MB)
    float* rbuf  = (float*)(gbuf + (size_t)N_NODES * OUT_DIM); // N*8 f32 (3.2 MB)

    // zero qcnt only (4 KB)
    hipMemsetAsync(d_ws, 0, 1024 * sizeof(int), stream);

    k_part2<<<NCHUNK, 256, 0, stream>>>(ei, (const u32*)x,
                                        W1l, b1, W1r, W2l, b2, W2r,
                                        qcnt, qbuf,
                                        tW1l, tW1r, tW2l, tW2r, tb1, tb2);
    k_l1<<<NBKT, 256, 0, stream>>>(x, qcnt, qbuf,
                                   tW1l, tW1r, tW2l, tW2r, tb1, tb2,
                                   gbuf, rbuf, (const u32*)x);
    k_l2<<<NBKT, 256, 0, stream>>>(gbuf, rbuf, qcnt, qbuf,
                                   (const u32*)x, d_out);
}